// Round 6
// baseline (308.029 us; speedup 1.0000x reference)
//
#include <hip/hip_runtime.h>
#include <hip/hip_bf16.h>

#define B_  128
#define S_  512
#define H_  64
#define E_  64
#define G3  192   // 3*H
#define V_  4996
#define VCHUNK 32
#define CHUNK  32            // time steps per output-flush chunk
#define NCHUNK (S_ / CHUNK)  // 16

typedef float f32x2 __attribute__((ext_vector_type(2)));
typedef float f32x4 __attribute__((ext_vector_type(4)));

__device__ __forceinline__ float sigmoidf_(float x) {
    return 1.0f / (1.0f + __expf(-x));
}

__device__ __forceinline__ float tanh_fast(float x) {
    x = fminf(fmaxf(x, -15.0f), 15.0f);
    const float e = __expf(2.0f * x);
    return (e - 1.0f) / (e + 1.0f);
}

// ---------------------------------------------------------------------------
// Kernel 1: pre-project the embedding table through the input kernels.
//   proj[dir][v][j] = sum_e emb[v][e] * W_dir[e][j] + bi_dir[j]
// ---------------------------------------------------------------------------
__global__ __launch_bounds__(192) void proj_kernel(
    const float* __restrict__ emb,
    const float* __restrict__ Wf, const float* __restrict__ bif,
    const float* __restrict__ Wb, const float* __restrict__ bib,
    float* __restrict__ proj)            // [2][V][192]
{
    const int dir = blockIdx.y;
    const float* W  = dir ? Wb  : Wf;
    const float* bi = dir ? bib : bif;
    const int v0 = blockIdx.x * VCHUNK;
    const int j  = threadIdx.x;
    const int nrows = min(VCHUNK, V_ - v0);

    __shared__ __align__(16) float s_e[VCHUNK * E_];
    for (int i = j; i < nrows * E_; i += 192) s_e[i] = emb[(size_t)v0 * E_ + i];

    float wcol[E_];
    #pragma unroll
    for (int e = 0; e < E_; ++e) wcol[e] = W[e * G3 + j];
    const float bij = bi[j];
    __syncthreads();

    for (int r = 0; r < nrows; ++r) {
        const float4* x4 = (const float4*)(s_e + r * E_);
        float a0 = 0.f, a1 = 0.f, a2 = 0.f, a3 = 0.f;
        #pragma unroll
        for (int e4 = 0; e4 < 16; e4 += 4) {
            float4 h0 = x4[e4], h1 = x4[e4+1], h2 = x4[e4+2], h3 = x4[e4+3];
            a0 = fmaf(h0.x, wcol[4*e4+ 0], a0); a0 = fmaf(h0.y, wcol[4*e4+ 1], a0);
            a0 = fmaf(h0.z, wcol[4*e4+ 2], a0); a0 = fmaf(h0.w, wcol[4*e4+ 3], a0);
            a1 = fmaf(h1.x, wcol[4*e4+ 4], a1); a1 = fmaf(h1.y, wcol[4*e4+ 5], a1);
            a1 = fmaf(h1.z, wcol[4*e4+ 6], a1); a1 = fmaf(h1.w, wcol[4*e4+ 7], a1);
            a2 = fmaf(h2.x, wcol[4*e4+ 8], a2); a2 = fmaf(h2.y, wcol[4*e4+ 9], a2);
            a2 = fmaf(h2.z, wcol[4*e4+10], a2); a2 = fmaf(h2.w, wcol[4*e4+11], a2);
            a3 = fmaf(h3.x, wcol[4*e4+12], a3); a3 = fmaf(h3.y, wcol[4*e4+13], a3);
            a3 = fmaf(h3.z, wcol[4*e4+14], a3); a3 = fmaf(h3.w, wcol[4*e4+15], a3);
        }
        proj[((size_t)dir * V_ + v0 + r) * G3 + j] = ((a0 + a1) + (a2 + a3)) + bij;
    }
}

// Kernel 2: transpose recurrent kernels: Ut[dir][j][e] = U_dir[e][j]
__global__ void utrans_kernel(const float* __restrict__ Uf,
                              const float* __restrict__ Ub,
                              float* __restrict__ Ut)   // [2][192][64]
{
    const int dir = blockIdx.x;
    const float* U = dir ? Ub : Uf;
    float* o = Ut + (size_t)dir * G3 * H_;
    for (int k = threadIdx.x; k < G3 * H_; k += blockDim.x) {
        const int j = k / H_, e = k % H_;
        o[k] = U[e * G3 + j];
    }
}

// ---------------------------------------------------------------------------
// Kernel 3: the sequential scan. ONE WAVE per (batch row, direction):
// 64 lanes, lane u owns unit u and computes z (col u), r (col u+64) and the
// candidate (col u+128) entirely in-lane — no barriers, no shuffles (same-wave
// LDS ops are in-order). U columns live in 192 pinned VGPRs. xw is prefetched
// 4 steps ahead straight from global into registers (fully unrolled rotation).
// h history ring in LDS doubles as the output buffer, flushed per 32 steps.
// ---------------------------------------------------------------------------
__global__ __launch_bounds__(64)
__attribute__((amdgpu_waves_per_eu(1, 1)))
void gru_scan5(
    const int*   __restrict__ inputs,   // [B,S]
    const float* __restrict__ proj,     // [2][V][192]
    const float* __restrict__ Ut,       // [2][192][64]
    const float* __restrict__ brf, const float* __restrict__ brb,
    float* __restrict__ gru_out)        // [B,S,2H]
{
    const int b    = blockIdx.x >> 1;
    const int dir  = blockIdx.x & 1;
    const int lane = threadIdx.x;          // == unit

    const float* eproj = proj + (size_t)dir * V_ * G3;
    const float* br    = dir ? brb : brf;

    __shared__ int s_idx[S_];
    __shared__ __align__(16) float s_hist[CHUNK + 1][H_];  // row 0 = carry-in

    for (int t = lane; t < S_; t += 64) s_idx[t] = inputs[b * S_ + t];
    s_hist[0][lane] = 0.0f;

    // U columns for this unit's three gates: 48 f32x4 = 192 VGPRs, pinned.
    f32x4 uz[16], ur[16], uc[16];
    {
        const f32x4* pz = (const f32x4*)(Ut + ((size_t)dir * G3 + lane      ) * H_);
        const f32x4* pr = (const f32x4*)(Ut + ((size_t)dir * G3 + lane + 64 ) * H_);
        const f32x4* pc = (const f32x4*)(Ut + ((size_t)dir * G3 + lane + 128) * H_);
        #pragma unroll
        for (int k = 0; k < 16; ++k) { uz[k] = pz[k]; ur[k] = pr[k]; uc[k] = pc[k]; }
        #pragma unroll
        for (int k = 0; k < 16; ++k) {
            asm volatile("" : "+v"(uz[k]));
            asm volatile("" : "+v"(ur[k]));
            asm volatile("" : "+v"(uc[k]));
        }
    }
    const float br0 = br[lane], br1 = br[lane + 64], br2 = br[lane + 128];
    float hprev = 0.0f;

    // 4-step-ahead xw prefetch (rotating, fully unrolled => registers)
    float xwp[4][3];
    int   tokp[4];
    auto pref = [&](int tstep, int p) {
        if (tstep < S_) {
            const int ttp = dir ? (S_ - 1 - tstep) : tstep;
            int tk = s_idx[ttp];
            tk = __builtin_amdgcn_readfirstlane(tk);
            tokp[p] = tk;
            const float* rowp = eproj + (size_t)tk * G3;
            xwp[p][0] = rowp[lane];
            xwp[p][1] = rowp[lane + 64];
            xwp[p][2] = rowp[lane + 128];
        }
    };
    #pragma unroll
    for (int p = 0; p < 4; ++p) pref(p, p);

    for (int c = 0; c < NCHUNK; ++c) {
        const int base = c * CHUNK;

        for (int t0 = 0; t0 < CHUNK; t0 += 4) {
            #pragma unroll
            for (int p = 0; p < 4; ++p) {
                const int t    = base + t0 + p;
                const int tok  = tokp[p];
                const float xw0 = xwp[p][0];
                const float xw1 = xwp[p][1];
                const float xw2 = xwp[p][2];

                // rec = h . U[:,col] for the three columns (broadcast h reads)
                const f32x4* h4 = (const f32x4*)s_hist[t0 + p];
                f32x4 az = {0,0,0,0}, ar4 = {0,0,0,0}, ac4 = {0,0,0,0};
                #pragma unroll
                for (int k = 0; k < 16; ++k) {
                    const f32x4 hv = h4[k];
                    az  += hv * uz[k];
                    ar4 += hv * ur[k];
                    ac4 += hv * uc[k];
                }
                const float d0 = (az.x  + az.y ) + (az.z  + az.w ) + br0;
                const float d1 = (ar4.x + ar4.y) + (ar4.z + ar4.w) + br1;
                const float d2 = (ac4.x + ac4.y) + (ac4.z + ac4.w) + br2;

                const float z    = sigmoidf_(xw0 + d0);
                const float r    = sigmoidf_(xw1 + d1);
                const float hh   = tanh_fast(xw2 + r * d2);
                const float hnew = z * hprev + (1.0f - z) * hh;
                const float res  = (tok != 0) ? hnew : hprev;   // mask_zero
                hprev = res;
                s_hist[t0 + p + 1][lane] = res;

                pref(t + 4, p);   // refill this phase slot
            }
        }

        // flush 32 steps of h to global (buffered, off the per-step path)
        #pragma unroll
        for (int q = 0; q < 8; ++q) {
            const int row  = 1 + q * 4 + (lane >> 4);
            const int col  = (lane & 15) * 4;
            const int step = base + row - 1;
            const int tts  = dir ? (S_ - 1 - step) : step;
            *(float4*)(gru_out + ((size_t)(b * S_ + tts)) * (2 * H_)
                       + dir * H_ + col) = *(const float4*)(&s_hist[row][col]);
        }
        s_hist[0][lane] = hprev;   // carry for next chunk
    }
}

// x1 = sigmoid(gru_out @ w1 + b1), x2 = sigmoid(gru_out @ w2 + b2)
__global__ __launch_bounds__(256) void head_kernel(
    const float* __restrict__ gru,      // [B*S, 2H]
    const float* __restrict__ w1, const float* __restrict__ b1,
    const float* __restrict__ w2, const float* __restrict__ b2,
    float* __restrict__ x1, float* __restrict__ x2)
{
    __shared__ __align__(16) float s_w1[2 * H_];
    __shared__ __align__(16) float s_w2[2 * H_];
    const int tid = threadIdx.x;
    if (tid < 2 * H_)      s_w1[tid]          = w1[tid];
    else                   s_w2[tid - 2 * H_] = w2[tid - 2 * H_];
    __syncthreads();

    const int i = blockIdx.x * 256 + tid;
    const float4* g4 = (const float4*)(gru + (size_t)i * (2 * H_));
    float a1 = b1[0], a2 = b2[0];
    #pragma unroll
    for (int k = 0; k < (2 * H_) / 4; ++k) {
        const float4 v  = g4[k];
        const float4 q1 = ((const float4*)s_w1)[k];
        const float4 q2 = ((const float4*)s_w2)[k];
        a1 += v.x * q1.x + v.y * q1.y + v.z * q1.z + v.w * q1.w;
        a2 += v.x * q2.x + v.y * q2.y + v.z * q2.z + v.w * q2.w;
    }
    x1[i] = sigmoidf_(a1);
    x2[i] = sigmoidf_(a2);
}

extern "C" void kernel_launch(void* const* d_in, const int* in_sizes, int n_in,
                              void* d_out, int out_size, void* d_ws, size_t ws_size,
                              hipStream_t stream) {
    (void)in_sizes; (void)n_in; (void)ws_size; (void)out_size;

    const int*   inputs = (const int*)  d_in[0];
    const float* emb    = (const float*)d_in[1];
    const float* Wf     = (const float*)d_in[2];
    const float* Uf     = (const float*)d_in[3];
    const float* bif    = (const float*)d_in[4];
    const float* brf    = (const float*)d_in[5];
    const float* Wb     = (const float*)d_in[6];
    const float* Ub     = (const float*)d_in[7];
    const float* bib    = (const float*)d_in[8];
    const float* brb    = (const float*)d_in[9];
    const float* w1     = (const float*)d_in[10];
    const float* b1     = (const float*)d_in[11];
    const float* w2     = (const float*)d_in[12];
    const float* b2     = (const float*)d_in[13];

    float* out = (float*)d_out;
    float* x1  = out;                       // [B*S]
    float* x2  = out + (size_t)B_ * S_;     // [B*S]
    float* gru = out + (size_t)2 * B_ * S_; // [B*S, 2H]

    // workspace: proj [2][V][192] floats, then Ut [2][192][64] floats (~7.77 MB)
    float* proj = (float*)d_ws;
    float* Ut   = proj + (size_t)2 * V_ * G3;

    proj_kernel<<<dim3((V_ + VCHUNK - 1) / VCHUNK, 2), 192, 0, stream>>>(
        emb, Wf, bif, Wb, bib, proj);
    utrans_kernel<<<2, 256, 0, stream>>>(Uf, Ub, Ut);

    gru_scan5<<<B_ * 2, 64, 0, stream>>>(inputs, proj, Ut, brf, brb, gru);

    head_kernel<<<(B_ * S_) / 256, 256, 0, stream>>>(gru, w1, b1, w2, b2, x1, x2);
}